// Round 4
// baseline (306.149 us; speedup 1.0000x reference)
//
#include <hip/hip_runtime.h>
#include <hip/hip_bf16.h>

typedef __attribute__((ext_vector_type(8))) short bf16x8;
typedef __attribute__((ext_vector_type(4))) float f32x4;

#define N_OUT 65536
#define CIN   256
#define COUT  512
#define BM    128
#define BK    32
#define NKS   64    // 2048 / 32 K-steps

__device__ __forceinline__ unsigned short f2bf(float f) {
  union { __hip_bfloat16 h; unsigned short u; } c;
  c.h = __float2bfloat16(f);
  return c.u;
}

__device__ __forceinline__ bf16x8 pack8(f32x4 a, f32x4 b) {
  unsigned short u[8];
  u[0] = f2bf(a.x); u[1] = f2bf(a.y); u[2] = f2bf(a.z); u[3] = f2bf(a.w);
  u[4] = f2bf(b.x); u[5] = f2bf(b.y); u[6] = f2bf(b.z); u[7] = f2bf(b.w);
  return *reinterpret_cast<bf16x8*>(u);
}

// async global -> LDS DMA, 16B per lane (dst = wave-uniform base + lane*16)
__device__ __forceinline__ void gload_lds16f(const float* g, float* l) {
  __builtin_amdgcn_global_load_lds(
      (const __attribute__((address_space(1))) void*)g,
      (__attribute__((address_space(3))) void*)l, 16, 0, 0);
}
__device__ __forceinline__ void gload_lds16u(const unsigned short* g, unsigned short* l) {
  __builtin_amdgcn_global_load_lds(
      (const __attribute__((address_space(1))) void*)g,
      (__attribute__((address_space(3))) void*)l, 16, 0, 0);
}

// --- weight prep: W[k][n] f32 -> Wt bf16 tiled [kb][slot][n][w]:
//     Wt[kb*16384 + s*4096 + n*8 + w] = bf16(W[(kb*32 + s*8 + w)*512 + n])
//     (one 32KB contiguous panel per kb; linear DMA; conflict-free wave read)
__global__ void wprep_kernel(const float* __restrict__ W, unsigned short* __restrict__ Wt) {
  int idx = blockIdx.x * blockDim.x + threadIdx.x;   // 131072 = 64*4*512
  if (idx >= 64 * 4 * COUT) return;
  int n  = idx & (COUT - 1);
  int s  = (idx >> 9) & 3;
  int kb = idx >> 11;
  unsigned short tmp[8];
#pragma unroll
  for (int w = 0; w < 8; ++w)
    tmp[w] = f2bf(W[(size_t)(kb * 32 + s * 8 + w) * COUT + n]);   // coalesced over n
  *reinterpret_cast<bf16x8*>(Wt + ((size_t)kb * 16384 + s * 4096 + n * 8)) =
      *reinterpret_cast<bf16x8*>(tmp);
}

// --- main GEMM: out_raw = gather(data,neigh) @ Wt  (+ per-block column partials)
__global__ __launch_bounds__(512, 2) void gemm_kernel(
    const float* __restrict__ data,
    const int*   __restrict__ neigh,
    const unsigned short* __restrict__ Wt,
    float* __restrict__ out,
    float* __restrict__ psum,
    float* __restrict__ psq)
{
  // A ring: fp32 [3][128 rows][32 k], 16B chunks XOR-swizzled (chunk c of row r
  //   at slot c^(r&7); DMA dst linear, global src pre-swizzled -- rule 21).
  // B ring: bf16 [3][4 slots][512 n][8 kk], linear DMA, conflict-free read.
  __shared__ union {
    struct {
      float          a[3][BM * BK];     // 3 x 16 KB
      unsigned short b[3][BK * COUT];   // 3 x 32 KB
    } r;
    float st[4][COUT];                  // stats overlay (after final barrier)
  } sm;
  __shared__ unsigned int offs[BM * 8];

  const int tid = threadIdx.x;
  const int l   = tid & 63;
  const int w   = tid >> 6;         // 8 waves
  const int wr  = w >> 2;           // 0..1 (64-row strip)
  const int wc  = w & 3;            // 0..3 (128-col strip)
  const int lg  = l >> 4;
  const int lm  = l & 15;
  const int m0  = blockIdx.x * BM;

  f32x4 acc[4][8];
#pragma unroll
  for (int i = 0; i < 4; ++i)
#pragma unroll
    for (int j = 0; j < 8; ++j) acc[i][j] = (f32x4){0.f, 0.f, 0.f, 0.f};

  bf16x8 af[4], bf[8];

  // neigh -> LDS offset table (float offsets into data; lgkm path)
  for (int e = tid; e < BM * 8; e += 512)
    offs[e] = ((unsigned)neigh[(size_t)m0 * 8 + e]) << 8;
  __syncthreads();

  // A: 2 DMA ops/wave/step. Wave w covers rows w*16..w*16+15; op q: 8 rows.
  // lane l -> row base+(l>>3), LDS slot l&7 <- global chunk (l&7)^((l>>3)&7).
#define AISSUE(t_, buf_) do { \
    const int cn_ = (t_) >> 3; \
    const int k0_ = ((t_) & 7) * BK; \
    _Pragma("unroll") \
    for (int q_ = 0; q_ < 2; ++q_) { \
      int row_ = w * 16 + q_ * 8 + (l >> 3); \
      unsigned off_ = offs[row_ * 8 + cn_]; \
      const float* src_ = data + off_ + k0_ + (((l & 7) ^ ((l >> 3) & 7)) << 2); \
      gload_lds16f(src_, &sm.r.a[buf_][(w * 16 + q_ * 8) * BK]); \
    } \
  } while (0)

  // B: 4 DMA ops/wave/step, fully linear (panel is 32KB contiguous).
#define BISSUE(t_, buf_) do { \
    const unsigned short* bs_ = Wt + (size_t)(t_) * 16384; \
    _Pragma("unroll") \
    for (int p_ = 0; p_ < 4; ++p_) \
      gload_lds16u(bs_ + (w * 4 + p_) * 512 + l * 8, &sm.r.b[buf_][(w * 4 + p_) * 512]); \
  } while (0)

#define LOAD_AF(buf_) do { \
    _Pragma("unroll") \
    for (int mi_ = 0; mi_ < 4; ++mi_) { \
      int R_ = wr * 64 + mi_ * 16 + lm; \
      const f32x4* b_ = reinterpret_cast<const f32x4*>(&sm.r.a[buf_][R_ * BK]); \
      f32x4 x0_ = b_[(2 * lg)     ^ (R_ & 7)]; \
      f32x4 x1_ = b_[(2 * lg + 1) ^ (R_ & 7)]; \
      af[mi_] = pack8(x0_, x1_); \
    } \
  } while (0)

#define LOAD_BF(buf_) do { \
    _Pragma("unroll") \
    for (int ni_ = 0; ni_ < 8; ++ni_) \
      bf[ni_] = *reinterpret_cast<const bf16x8*>( \
          &sm.r.b[buf_][lg * 4096 + (wc * 128 + lm + ni_ * 16) * 8]); \
  } while (0)

#define DO_MFMA() do { \
    _Pragma("unroll") \
    for (int mi_ = 0; mi_ < 4; ++mi_) \
      _Pragma("unroll") \
      for (int ni_ = 0; ni_ < 8; ++ni_) \
        acc[mi_][ni_] = __builtin_amdgcn_mfma_f32_16x16x32_bf16(af[mi_], bf[ni_], acc[mi_][ni_], 0, 0, 0); \
  } while (0)

  // ---- prologue: steps 0 and 1 in flight (6 DMA ops/wave each)
  BISSUE(0, 0); AISSUE(0, 0);
  BISSUE(1, 1); AISSUE(1, 1);

  int bufc = 0, bufp = 2;
#pragma unroll 1
  for (int t = 0; t < NKS - 2; ++t) {
    // prefetch step t+2 into the buffer last read at step t-1 (post-barrier: safe)
    BISSUE(t + 2, bufp);
    AISSUE(t + 2, bufp);
    // counted wait: own 12 newer ops (steps t+1,t+2) stay in flight; step t retired
    asm volatile("s_waitcnt vmcnt(12)" ::: "memory");
    __builtin_amdgcn_s_barrier();          // all waves' step-t DMA landed
    LOAD_AF(bufc);
    LOAD_BF(bufc);
    DO_MFMA();
    __builtin_amdgcn_s_barrier();          // WAR: reads done before next overwrite
    bufc = (bufc == 2) ? 0 : bufc + 1;
    bufp = (bufp == 2) ? 0 : bufp + 1;
  }
  // ---- tail step NKS-2 (6 own ops still in flight for NKS-1)
  asm volatile("s_waitcnt vmcnt(6)" ::: "memory");
  __builtin_amdgcn_s_barrier();
  LOAD_AF(bufc); LOAD_BF(bufc); DO_MFMA();
  bufc = (bufc == 2) ? 0 : bufc + 1;
  // ---- tail step NKS-1
  asm volatile("s_waitcnt vmcnt(0)" ::: "memory");
  __builtin_amdgcn_s_barrier();
  LOAD_AF(bufc); LOAD_BF(bufc); DO_MFMA();

  // ---- epilogue 1: raw out (C layout: col = lane&15, row = (lane>>4)*4 + reg)
#pragma unroll
  for (int mi = 0; mi < 4; ++mi) {
#pragma unroll
    for (int r = 0; r < 4; ++r) {
      size_t row = (size_t)(m0 + wr * 64 + mi * 16 + lg * 4 + r);
      float* op = out + row * COUT + wc * 128 + lm;
#pragma unroll
      for (int ni = 0; ni < 8; ++ni) op[ni * 16] = acc[mi][ni][r];
    }
  }

  // ---- epilogue 2: deterministic per-block column sums/sumsq
  __syncthreads();   // all LDS reads done before st overlay is written
#pragma unroll
  for (int ni = 0; ni < 8; ++ni) {
    float s1 = 0.f, s2 = 0.f;
#pragma unroll
    for (int mi = 0; mi < 4; ++mi)
#pragma unroll
      for (int r = 0; r < 4; ++r) { float v = acc[mi][ni][r]; s1 += v; s2 += v * v; }
    s1 += __shfl_xor(s1, 16, 64); s1 += __shfl_xor(s1, 32, 64);
    s2 += __shfl_xor(s2, 16, 64); s2 += __shfl_xor(s2, 32, 64);
    if (l < 16) {
      sm.st[wr][wc * 128 + ni * 16 + l]     = s1;
      sm.st[2 + wr][wc * 128 + ni * 16 + l] = s2;
    }
  }
  __syncthreads();
  {
    float S = sm.st[0][tid] + sm.st[1][tid];
    float Q = sm.st[2][tid] + sm.st[3][tid];
    psum[(size_t)blockIdx.x * COUT + tid] = S;
    psq [(size_t)blockIdx.x * COUT + tid] = Q;
  }
#undef AISSUE
#undef BISSUE
#undef LOAD_AF
#undef LOAD_BF
#undef DO_MFMA
}

// --- stats reduction, stage 1: 512 -> 64 partials per column
__global__ void reduce1_kernel(const float* __restrict__ psum, const float* __restrict__ psq,
                               float* __restrict__ p2) {
  int c = threadIdx.x, b = blockIdx.x;
  float s = 0.f, q = 0.f;
#pragma unroll
  for (int j = 0; j < 8; ++j) {
    s += psum[(size_t)(b * 8 + j) * COUT + c];
    q += psq [(size_t)(b * 8 + j) * COUT + c];
  }
  p2[b * 1024 + c] = s;
  p2[b * 1024 + 512 + c] = q;
}

// --- stats reduction, stage 2: mean/var -> per-column scale/shift
__global__ void reduce2_kernel(const float* __restrict__ p2,
                               const float* __restrict__ gamma,
                               const float* __restrict__ beta,
                               float* __restrict__ scsh) {
  int c = threadIdx.x;
  float s = 0.f, q = 0.f;
  for (int b = 0; b < 64; ++b) { s += p2[b * 1024 + c]; q += p2[b * 1024 + 512 + c]; }
  float mean = s * (1.f / 65536.f);
  float var  = q * (1.f / 65536.f) - mean * mean;
  float rs   = rsqrtf(var + 1e-5f);
  float sc   = gamma[c] * rs;
  scsh[c] = sc;
  scsh[COUT + c] = beta[c] - mean * sc;   // conv bias cancels in BN
}

// --- apply BN in-place
__global__ void bn_kernel(float* __restrict__ out, const float* __restrict__ scsh) {
  __shared__ float sc[COUT], sh[COUT];
  int t = threadIdx.x;
  sc[t] = scsh[t];
  sh[t] = scsh[COUT + t];
  __syncthreads();
  f32x4* o4 = reinterpret_cast<f32x4*>(out);
  const size_t total  = (size_t)N_OUT * COUT / 4;
  const size_t stride = (size_t)gridDim.x * blockDim.x;
  for (size_t i = (size_t)blockIdx.x * blockDim.x + t; i < total; i += stride) {
    f32x4 v = o4[i];
    int c = ((int)(i & 127)) * 4;
    v.x = v.x * sc[c]     + sh[c];
    v.y = v.y * sc[c + 1] + sh[c + 1];
    v.z = v.z * sc[c + 2] + sh[c + 2];
    v.w = v.w * sc[c + 3] + sh[c + 3];
    o4[i] = v;
  }
}

extern "C" void kernel_launch(void* const* d_in, const int* in_sizes, int n_in,
                              void* d_out, int out_size, void* d_ws, size_t ws_size,
                              hipStream_t stream) {
  const float* data   = (const float*)d_in[0];
  const float* weight = (const float*)d_in[1];
  const float* gamma  = (const float*)d_in[3];
  const float* beta   = (const float*)d_in[4];
  const int*   neigh  = (const int*)d_in[5];
  float* out = (float*)d_out;

  char* ws = (char*)d_ws;
  unsigned short* Wt = (unsigned short*)ws;                        // 2 MB
  float* psum = (float*)(ws + (2u << 20));                         // 1 MB
  float* psq  = (float*)(ws + (3u << 20));                         // 1 MB
  float* p2   = (float*)(ws + (4u << 20));                         // 256 KB
  float* scsh = (float*)(ws + (4u << 20) + (256u << 10));          // 4 KB

  wprep_kernel<<<512, 256, 0, stream>>>(weight, Wt);
  gemm_kernel<<<N_OUT / BM, 512, 0, stream>>>(data, neigh, Wt, out, psum, psq);
  reduce1_kernel<<<64, 512, 0, stream>>>(psum, psq, p2);
  reduce2_kernel<<<1, 512, 0, stream>>>(p2, gamma, beta, scsh);
  bn_kernel<<<2048, 512, 0, stream>>>(out, scsh);
}